// Round 11
// baseline (395.648 us; speedup 1.0000x reference)
//
#include <hip/hip_runtime.h>

#define NN 100000
#define NE 1600000
#define NLB 256            // lsort chunks
#define CHUNK (NE / NLB)   // 6250 edges per chunk
#define NB 196             // dst buckets (dst >> 9)
#define BN 512             // nodes per bucket

__device__ __forceinline__ float bf2f(unsigned short u) {
    return __uint_as_float(((unsigned int)u) << 16);
}
__device__ __forceinline__ unsigned short f2bf(float f) {
    unsigned int u = __float_as_uint(f);
    return (unsigned short)((u + 0x7FFFu + ((u >> 16) & 1u)) >> 16);
}

// ================= fused front end: blocks [0,NLB) sort edges, rest do z1=x@W1
// (validated R10)
__global__ __launch_bounds__(256) void k_front(const int* __restrict__ src,
                                               const int* __restrict__ dst,
                                               int* __restrict__ pairs,
                                               int* __restrict__ tstart,
                                               int* __restrict__ tcnt,
                                               int* __restrict__ btot,
                                               const float* __restrict__ x,
                                               const float* __restrict__ W1,
                                               unsigned short* __restrict__ z1) {
    __shared__ float Ws[128 * 32];
    __shared__ float xs[32][129];
    __shared__ int cnt[NB];
    __shared__ int sc[256];
    __shared__ int cur[NB];
    int tid = threadIdx.x;
    if (blockIdx.x < NLB) {
        int blk = blockIdx.x;
        int e0 = blk * CHUNK;
        for (int i = tid; i < NB; i += 256) cnt[i] = 0;
        __syncthreads();
        for (int i = tid; i < CHUNK; i += 256) atomicAdd(&cnt[dst[e0 + i] >> 9], 1);
        __syncthreads();
        sc[tid] = (tid < NB) ? cnt[tid] : 0;
        __syncthreads();
        for (int off = 1; off < 256; off <<= 1) {
            int v = (tid >= off) ? sc[tid - off] : 0;
            __syncthreads();
            sc[tid] += v;
            __syncthreads();
        }
        if (tid < NB) {
            int excl = sc[tid] - cnt[tid];
            cur[tid] = excl;
            tstart[blk * NB + tid] = excl;
            tcnt[blk * NB + tid]   = cnt[tid];
            atomicAdd(&btot[tid], cnt[tid]);
        }
        __syncthreads();
        for (int i = tid; i < CHUNK; i += 256) {
            int d = dst[e0 + i], s = src[e0 + i];
            int p = atomicAdd(&cur[d >> 9], 1);
            pairs[e0 + p] = ((d & (BN - 1)) << 17) | s;
        }
    } else {
        int bid = blockIdx.x - NLB;
        for (int i = tid; i < 1024; i += 256) {
            float4 w = ((const float4*)W1)[i];
            float* d = &Ws[i * 4];
            d[0] = w.x; d[1] = w.y; d[2] = w.z; d[3] = w.w;
        }
        int n_loc = tid >> 3;
        int j0    = (tid & 7) * 4;
        for (int base = bid * 32; base < NN; base += 1024 * 32) {
            __syncthreads();
            for (int t = tid; t < 1024; t += 256) {
                int n = t >> 5, c = t & 31;
                float4 v = ((const float4*)(x + (size_t)(base + n) * 128))[c];
                float* d = &xs[n][c * 4];
                d[0] = v.x; d[1] = v.y; d[2] = v.z; d[3] = v.w;
            }
            __syncthreads();
            float a0 = 0.f, a1 = 0.f, a2 = 0.f, a3 = 0.f;
            #pragma unroll 8
            for (int k = 0; k < 128; k++) {
                float xv = xs[n_loc][k];
                float4 w = *(const float4*)&Ws[k * 32 + j0];
                a0 = fmaf(xv, w.x, a0); a1 = fmaf(xv, w.y, a1);
                a2 = fmaf(xv, w.z, a2); a3 = fmaf(xv, w.w, a3);
            }
            ushort4 o = { f2bf(a0), f2bf(a1), f2bf(a2), f2bf(a3) };
            *(ushort4*)&z1[(size_t)(base + n_loc) * 32 + j0] = o;
        }
    }
}

// ============================= pass 2: per-bucket CSR via wave segment-walks
// (validated R8-R10)
__global__ __launch_bounds__(1024) void k_build(const int* __restrict__ pairs,
                                                const int* __restrict__ tstart,
                                                const int* __restrict__ tcnt,
                                                const int* __restrict__ btot,
                                                int* __restrict__ csr,
                                                int* __restrict__ row,
                                                int* __restrict__ rend) {
    __shared__ int segS[NLB], segL[NLB];
    __shared__ int ncnt[BN];
    __shared__ int nbase[BN + 1];
    __shared__ int sc[256];
    __shared__ int sc2[256];
    __shared__ int base_s;
    int tid = threadIdx.x, b = blockIdx.x;

    if (tid < 256) sc2[tid] = (tid < NB) ? btot[tid] : 0;
    __syncthreads();
    for (int off = 1; off < 256; off <<= 1) {
        int v = 0;
        if (tid < 256 && tid >= off) v = sc2[tid - off];
        __syncthreads();
        if (tid < 256) sc2[tid] += v;
        __syncthreads();
    }
    if (tid == 0) base_s = (b == 0) ? 0 : sc2[b - 1];
    if (tid < NLB) {
        segS[tid] = tid * CHUNK + tstart[tid * NB + b];
        segL[tid] = tcnt[tid * NB + b];
    }
    for (int i = tid; i < BN; i += 1024) ncnt[i] = 0;
    __syncthreads();

    int wave = tid >> 6, lane = tid & 63;
    for (int s = wave; s < NLB; s += 16) {
        int st = segS[s], len = segL[s];
        for (int i = lane; i < len; i += 64)
            atomicAdd(&ncnt[pairs[st + i] >> 17], 1);
    }
    __syncthreads();

    int c0 = 0, c1 = 0, tsum = 0;
    if (tid < 256) { c0 = ncnt[2 * tid]; c1 = ncnt[2 * tid + 1]; tsum = c0 + c1; sc[tid] = tsum; }
    __syncthreads();
    for (int off = 1; off < 256; off <<= 1) {
        int v = 0;
        if (tid < 256 && tid >= off) v = sc[tid - off];
        __syncthreads();
        if (tid < 256) sc[tid] += v;
        __syncthreads();
    }
    if (tid < 256) {
        int excl = sc[tid] - tsum;
        nbase[2 * tid]     = excl;
        nbase[2 * tid + 1] = excl + c0;
        if (tid == 255) nbase[BN] = sc[255];
    }
    __syncthreads();

    int base = base_s;
    if (tid < BN) {
        int n = b * BN + tid;
        if (n < NN) { row[n] = base + nbase[tid]; rend[n] = base + nbase[tid + 1]; }
        ncnt[tid] = 0;
    }
    __syncthreads();

    for (int s = wave; s < NLB; s += 16) {
        int st = segS[s], len = segL[s];
        for (int i = lane; i < len; i += 64) {
            int p = pairs[st + i];
            int ln = p >> 17;
            int pos = atomicAdd(&ncnt[ln], 1);
            csr[base + nbase[ln] + pos] = p & 0x1FFFF;
        }
    }
}

// ==== fused conv1 tail: gather(z1b)+self+b1+relu -> t; h=relu(t@W2+b2); z2=h@W3
// Grid 3125 x 256: one 32-node group per block.
__global__ __launch_bounds__(256) void k_mid(const unsigned short* __restrict__ z1,
                                             const int* __restrict__ row,
                                             const int* __restrict__ rend,
                                             const int* __restrict__ csr,
                                             const float* __restrict__ b1,
                                             const float* __restrict__ W2,
                                             const float* __restrict__ b2,
                                             const float* __restrict__ W3,
                                             unsigned short* __restrict__ z2) {
    __shared__ float W2s[32 * 64];
    __shared__ float W3s[64 * 64];
    __shared__ float ts[32][33];
    __shared__ float hs[32 * 68];
    __shared__ float b1s[32], b2s[64];
    int tid = threadIdx.x;
    for (int i = tid; i < 512; i += 256) {
        float4 w = ((const float4*)W2)[i];
        float* d = &W2s[i * 4];
        d[0] = w.x; d[1] = w.y; d[2] = w.z; d[3] = w.w;
    }
    for (int i = tid; i < 1024; i += 256) {
        float4 w = ((const float4*)W3)[i];
        float* d = &W3s[i * 4];
        d[0] = w.x; d[1] = w.y; d[2] = w.z; d[3] = w.w;
    }
    if (tid < 32) b1s[tid] = b1[tid];
    if (tid >= 64 && tid < 128) b2s[tid - 64] = b2[tid - 64];
    __syncthreads();

    int base = blockIdx.x * 32;   // 3125*32 == NN exactly
    // phase A: gather. 8 half-waves; half-wave hw handles nodes hw*4 + r.
    {
        int hw = tid >> 5, f = tid & 31;
        for (int r = 0; r < 4; r++) {
            int ln = hw * 4 + r;
            int n = base + ln;
            int j = row[n], e = rend[n];
            float a0 = bf2f(z1[(size_t)n * 32 + f]);   // self term
            float a1 = 0.f, a2 = 0.f, a3 = 0.f;
            for (; j + 3 < e; j += 4) {
                int i0 = csr[j], i1 = csr[j + 1], i2 = csr[j + 2], i3 = csr[j + 3];
                a0 += bf2f(z1[(size_t)i0 * 32 + f]);
                a1 += bf2f(z1[(size_t)i1 * 32 + f]);
                a2 += bf2f(z1[(size_t)i2 * 32 + f]);
                a3 += bf2f(z1[(size_t)i3 * 32 + f]);
            }
            for (; j < e; j++) a0 += bf2f(z1[(size_t)csr[j] * 32 + f]);
            ts[ln][f] = fmaxf(((a0 + a1) + (a2 + a3)) + b1s[f], 0.f);
        }
    }
    __syncthreads();
    int n2 = tid >> 4;
    int j0 = (tid & 15) * 4;
    int na = 2 * n2, nb = 2 * n2 + 1;
    {   // phase B: h = relu(t@W2+b2)
        float a00=0,a01=0,a02=0,a03=0,a10=0,a11=0,a12=0,a13=0;
        #pragma unroll 8
        for (int k = 0; k < 32; k++) {
            float t0 = ts[na][k], t1 = ts[nb][k];
            float4 w = *(const float4*)&W2s[k * 64 + j0];
            a00=fmaf(t0,w.x,a00); a01=fmaf(t0,w.y,a01); a02=fmaf(t0,w.z,a02); a03=fmaf(t0,w.w,a03);
            a10=fmaf(t1,w.x,a10); a11=fmaf(t1,w.y,a11); a12=fmaf(t1,w.z,a12); a13=fmaf(t1,w.w,a13);
        }
        *(float4*)&hs[na * 68 + j0] = make_float4(fmaxf(a00+b2s[j0],0.f), fmaxf(a01+b2s[j0+1],0.f),
                                                  fmaxf(a02+b2s[j0+2],0.f), fmaxf(a03+b2s[j0+3],0.f));
        *(float4*)&hs[nb * 68 + j0] = make_float4(fmaxf(a10+b2s[j0],0.f), fmaxf(a11+b2s[j0+1],0.f),
                                                  fmaxf(a12+b2s[j0+2],0.f), fmaxf(a13+b2s[j0+3],0.f));
    }
    __syncthreads();
    {   // phase C: z2 = h@W3 (b3 deferred past aggregation)
        float a00=0,a01=0,a02=0,a03=0,a10=0,a11=0,a12=0,a13=0;
        #pragma unroll 8
        for (int k = 0; k < 64; k++) {
            float h0 = hs[na * 68 + k], h1 = hs[nb * 68 + k];
            float4 w = *(const float4*)&W3s[k * 64 + j0];
            a00=fmaf(h0,w.x,a00); a01=fmaf(h0,w.y,a01); a02=fmaf(h0,w.z,a02); a03=fmaf(h0,w.w,a03);
            a10=fmaf(h1,w.x,a10); a11=fmaf(h1,w.y,a11); a12=fmaf(h1,w.z,a12); a13=fmaf(h1,w.w,a13);
        }
        ushort4 oa = { f2bf(a00), f2bf(a01), f2bf(a02), f2bf(a03) };
        ushort4 ob = { f2bf(a10), f2bf(a11), f2bf(a12), f2bf(a13) };
        *(ushort4*)&z2[(size_t)(base + na) * 64 + j0] = oa;
        *(ushort4*)&z2[(size_t)(base + nb) * 64 + j0] = ob;
    }
}

// ==== fused conv2 tail: gather(z2b)+self+b3+relu -> u; out=relu(u@W4+b4)+pool
// Grid 3125 x 256.
__global__ __launch_bounds__(256) void k_final(const unsigned short* __restrict__ z2,
                                               const int* __restrict__ row,
                                               const int* __restrict__ rend,
                                               const int* __restrict__ csr,
                                               const float* __restrict__ b3,
                                               const float* __restrict__ W4,
                                               const float* __restrict__ b4,
                                               float* __restrict__ out,
                                               float* __restrict__ gpool) {
    __shared__ float W4s[64 * 64];
    __shared__ float us[32 * 68];
    __shared__ float b3s[64], b4s[64], pool[64];
    int tid = threadIdx.x;
    for (int i = tid; i < 1024; i += 256) {
        float4 w = ((const float4*)W4)[i];
        float* d = &W4s[i * 4];
        d[0] = w.x; d[1] = w.y; d[2] = w.z; d[3] = w.w;
    }
    if (tid < 64) { b3s[tid] = b3[tid]; pool[tid] = 0.f; }
    if (tid >= 64 && tid < 128) b4s[tid - 64] = b4[tid - 64];
    __syncthreads();

    int base = blockIdx.x * 32;
    // phase A: gather. 4 waves; wave w handles nodes w*8 + r (r<8), unroll 8.
    {
        int w = tid >> 6, f = tid & 63;
        for (int r = 0; r < 8; r++) {
            int ln = w * 8 + r;
            int n = base + ln;
            int j = row[n], e = rend[n];
            float a0 = bf2f(z2[(size_t)n * 64 + f]);   // self term
            float a1 = 0.f, a2 = 0.f, a3 = 0.f;
            for (; j + 7 < e; j += 8) {
                int i0 = csr[j],     i1 = csr[j + 1], i2 = csr[j + 2], i3 = csr[j + 3];
                int i4 = csr[j + 4], i5 = csr[j + 5], i6 = csr[j + 6], i7 = csr[j + 7];
                float v0 = bf2f(z2[(size_t)i0 * 64 + f]);
                float v1 = bf2f(z2[(size_t)i1 * 64 + f]);
                float v2 = bf2f(z2[(size_t)i2 * 64 + f]);
                float v3 = bf2f(z2[(size_t)i3 * 64 + f]);
                float v4 = bf2f(z2[(size_t)i4 * 64 + f]);
                float v5 = bf2f(z2[(size_t)i5 * 64 + f]);
                float v6 = bf2f(z2[(size_t)i6 * 64 + f]);
                float v7 = bf2f(z2[(size_t)i7 * 64 + f]);
                a0 += v0 + v4; a1 += v1 + v5; a2 += v2 + v6; a3 += v3 + v7;
            }
            for (; j + 3 < e; j += 4) {
                int i0 = csr[j], i1 = csr[j + 1], i2 = csr[j + 2], i3 = csr[j + 3];
                a0 += bf2f(z2[(size_t)i0 * 64 + f]);
                a1 += bf2f(z2[(size_t)i1 * 64 + f]);
                a2 += bf2f(z2[(size_t)i2 * 64 + f]);
                a3 += bf2f(z2[(size_t)i3 * 64 + f]);
            }
            for (; j < e; j++) a0 += bf2f(z2[(size_t)csr[j] * 64 + f]);
            us[ln * 68 + f] = fmaxf(((a0 + a1) + (a2 + a3)) + b3s[f], 0.f);
        }
    }
    __syncthreads();
    int n2 = tid >> 4;
    int j0 = (tid & 15) * 4;
    int na = 2 * n2, nb = 2 * n2 + 1;
    float a00=0,a01=0,a02=0,a03=0,a10=0,a11=0,a12=0,a13=0;
    #pragma unroll 8
    for (int k = 0; k < 64; k++) {
        float u0 = us[na * 68 + k], u1 = us[nb * 68 + k];
        float4 w = *(const float4*)&W4s[k * 64 + j0];
        a00=fmaf(u0,w.x,a00); a01=fmaf(u0,w.y,a01); a02=fmaf(u0,w.z,a02); a03=fmaf(u0,w.w,a03);
        a10=fmaf(u1,w.x,a10); a11=fmaf(u1,w.y,a11); a12=fmaf(u1,w.z,a12); a13=fmaf(u1,w.w,a13);
    }
    float v00=fmaxf(a00+b4s[j0],0.f), v01=fmaxf(a01+b4s[j0+1],0.f);
    float v02=fmaxf(a02+b4s[j0+2],0.f), v03=fmaxf(a03+b4s[j0+3],0.f);
    float v10=fmaxf(a10+b4s[j0],0.f), v11=fmaxf(a11+b4s[j0+1],0.f);
    float v12=fmaxf(a12+b4s[j0+2],0.f), v13=fmaxf(a13+b4s[j0+3],0.f);
    *(float4*)&out[(size_t)(base + na) * 64 + j0] = make_float4(v00, v01, v02, v03);
    *(float4*)&out[(size_t)(base + nb) * 64 + j0] = make_float4(v10, v11, v12, v13);
    __syncthreads();
    atomicAdd(&pool[j0 + 0], v00 + v10);
    atomicAdd(&pool[j0 + 1], v01 + v11);
    atomicAdd(&pool[j0 + 2], v02 + v12);
    atomicAdd(&pool[j0 + 3], v03 + v13);
    __syncthreads();
    if (tid < 64) unsafeAtomicAdd(&gpool[tid], pool[tid]);
}

__global__ void k_pool(const float* __restrict__ gpool, float* __restrict__ out) {
    int t = threadIdx.x;
    if (t < 64) out[(size_t)NN * 64 + t] = gpool[t] * (1.0f / NN);
}

extern "C" void kernel_launch(void* const* d_in, const int* in_sizes, int n_in,
                              void* d_out, int out_size, void* d_ws, size_t ws_size,
                              hipStream_t stream) {
    const float* x  = (const float*)d_in[0];
    const int*   ei = (const int*)d_in[1];
    const float* W1 = (const float*)d_in[3];
    const float* b1 = (const float*)d_in[4];
    const float* W2 = (const float*)d_in[5];
    const float* b2 = (const float*)d_in[6];
    const float* W3 = (const float*)d_in[7];
    const float* b3 = (const float*)d_in[8];
    const float* W4 = (const float*)d_in[9];
    const float* b4 = (const float*)d_in[10];
    float* out = (float*)d_out;

    // ws (4B slots): tstart[NLB*NB] tcnt[NLB*NB] btot[196] gpool[64]
    //   row[NN] rend[NN] csr[NE] pairs[NE]
    //   z1b[NN*16 slots] z2b[NN*32 slots]      total ~36 MB (no agg buffers)
    int*   ip     = (int*)d_ws;
    int*   tstart = ip;                          // NLB*NB = 50176
    int*   tcnt   = ip + NLB * NB;               // 50176
    int*   btot   = ip + 2 * NLB * NB;           // 196
    float* gpool  = (float*)(ip + 2 * NLB * NB + 196);  // 64
    int*   row    = ip + 2 * NLB * NB + 260;     // NN
    int*   rend   = row + NN;                    // NN
    int*   csr    = rend + NN;                   // NE
    int*   pairs  = csr + NE;                    // NE
    unsigned short* z1b = (unsigned short*)(pairs + NE);          // NN*32 bf16
    unsigned short* z2b = (unsigned short*)(pairs + NE + NN * 16); // NN*64 bf16
    const int* src = ei;
    const int* dst = ei + NE;

    hipMemsetAsync(btot, 0, (196 + 64) * sizeof(int), stream);  // btot + gpool
    k_front<<<NLB + 1024, 256, 0, stream>>>(src, dst, pairs, tstart, tcnt, btot, x, W1, z1b);
    k_build<<<NB, 1024, 0, stream>>>(pairs, tstart, tcnt, btot, csr, row, rend);
    k_mid<<<NN / 32, 256, 0, stream>>>(z1b, row, rend, csr, b1, W2, b2, W3, z2b);
    k_final<<<NN / 32, 256, 0, stream>>>(z2b, row, rend, csr, b3, W4, b4, out, gpool);
    k_pool<<<1, 64, 0, stream>>>(gpool, out);
}